// Round 1
// 77.568 us; speedup vs baseline: 1.0242x; 1.0242x over previous
//
#include <hip/hip_runtime.h>
#include <stdint.h>

#define BATCH 16
#define TO 2048
#define TI 2048
#define DH 64
#define NITER (TI / 64)

typedef __attribute__((ext_vector_type(8))) short bf16x8;
typedef __attribute__((ext_vector_type(4))) float f32x4;

__device__ __forceinline__ unsigned short f2bf(float f) {
  uint32_t x = __float_as_uint(f);
  x += 0x7fffu + ((x >> 16) & 1u);   // RNE
  return (unsigned short)(x >> 16);
}

// Prologue: K fp32 -> bf16 (same [b][i][d] layout); V fp32 -> bf16 transposed [b][d][i].
__global__ __launch_bounds__(256) void convert_kv(
    const float* __restrict__ kg, const float* __restrict__ vg,
    unsigned short* __restrict__ k_bf, unsigned short* __restrict__ v_t) {
  __shared__ __align__(16) unsigned short vt[64][72];
  int b = blockIdx.y;
  int i0 = blockIdx.x * 64;
  int t = threadIdx.x;

  {
    const float4* src = (const float4*)(kg + ((size_t)b * TI + i0) * DH);
    ushort4* dst = (ushort4*)(k_bf + ((size_t)b * TI + i0) * DH);
#pragma unroll
    for (int u = 0; u < 4; ++u) {
      float4 f = src[t + 256 * u];
      ushort4 o;
      o.x = f2bf(f.x); o.y = f2bf(f.y); o.z = f2bf(f.z); o.w = f2bf(f.w);
      dst[t + 256 * u] = o;
    }
  }
  {
    const float4* src = (const float4*)(vg + ((size_t)b * TI + i0) * DH);
#pragma unroll
    for (int u = 0; u < 4; ++u) {
      int idx = t + 256 * u;
      int row = idx >> 4;
      int c4 = idx & 15;
      float4 f = src[idx];
      vt[c4 * 4 + 0][row] = f2bf(f.x);
      vt[c4 * 4 + 1][row] = f2bf(f.y);
      vt[c4 * 4 + 2][row] = f2bf(f.z);
      vt[c4 * 4 + 3][row] = f2bf(f.w);
    }
  }
  __syncthreads();
  {
    int dd = t >> 2, part = t & 3;
    ushort4* dst = (ushort4*)(v_t + ((size_t)b * DH + dd) * TI + i0 + part * 16);
#pragma unroll
    for (int u = 0; u < 4; ++u) {
      ushort4 o;
      o.x = vt[dd][part * 16 + u * 4 + 0];
      o.y = vt[dd][part * 16 + u * 4 + 1];
      o.z = vt[dd][part * 16 + u * 4 + 2];
      o.w = vt[dd][part * 16 + u * 4 + 3];
      dst[u] = o;
    }
  }
}

// Flash attention, S^T formulation, fixed-m softmax.
// Double-buffered LDS, ONE raw barrier per iteration with lgkmcnt-only drain:
// VMEM (mask prefetch + next-next KV chunk) stays in flight ACROSS barriers
// (T4 counted-wait discipline). Only cross-wave state is LDS -> lgkmcnt(0)
// before s_barrier is sufficient. Compiler inserts counted vmcnt() at the
// actual register consumption points.
//
// Body for iteration IC using LDS buffer CUR; consumes mask regs MCUR,
// prefetches next iteration's mask into MNXT (static double-buffer: no
// reg-copy -> no early vmcnt wait).
#define ATTN_BODY(CUR, IC, MCUR, MNXT)                                         \
  {                                                                            \
    if ((IC) < NITER - 1) {                                                    \
      _Pragma("unroll") for (int mt = 0; mt < 4; ++mt)                         \
          MNXT[mt] = *(const int4*)(mbase + mt * 16);                          \
      mbase += 64;                                                             \
      /* stage chunk IC+1 (regs, loaded one full iter ago) into other buf */   \
      *(uint4*)&k_lds[(CUR) ^ 1][row][part * 16] = ka0;                        \
      *(uint4*)&k_lds[(CUR) ^ 1][row][part * 16 + 8] = ka1;                    \
      *(uint4*)&v_lds[(CUR) ^ 1][row][part * 16] = va0;                        \
      *(uint4*)&v_lds[(CUR) ^ 1][row][part * 16 + 8] = va1;                    \
    }                                                                          \
    /* issue chunk IC+2 loads (consumed by ds_write at top of next body) */    \
    if ((IC) < NITER - 2) {                                                    \
      ka0 = kp[0]; ka1 = kp[1];                                                \
      va0 = vp[0]; va1 = vp[1];                                                \
      kp = (const uint4*)((const char*)kp + 64 * DH * 2);                      \
      vp = (const uint4*)((const char*)vp + 64 * 2);                           \
    }                                                                          \
    /* S^T = K x Q on buf[CUR] */                                              \
    f32x4 st[4];                                                               \
    _Pragma("unroll") for (int mt = 0; mt < 4; ++mt) {                         \
      bf16x8 kf0 = *(const bf16x8*)&k_lds[CUR][mt * 16 + ln15][quad * 8];      \
      bf16x8 kf1 = *(const bf16x8*)&k_lds[CUR][mt * 16 + ln15][32 + quad * 8]; \
      f32x4 acc = (f32x4){0.f, 0.f, 0.f, 0.f};                                 \
      acc = __builtin_amdgcn_mfma_f32_16x16x32_bf16(kf0, qf[0], acc, 0, 0, 0); \
      acc = __builtin_amdgcn_mfma_f32_16x16x32_bf16(kf1, qf[1], acc, 0, 0, 0); \
      st[mt] = acc;                                                            \
    }                                                                          \
    /* mask + exp (fixed m = 0) + partial l + P^T -> LDS (wave-private) */     \
    _Pragma("unroll") for (int mt = 0; mt < 4; ++mt) {                         \
      float p0 = (MCUR[mt].x != 0) ? __expf(st[mt][0]) : 0.f;                  \
      float p1 = (MCUR[mt].y != 0) ? __expf(st[mt][1]) : 0.f;                  \
      float p2 = (MCUR[mt].z != 0) ? __expf(st[mt][2]) : 0.f;                  \
      float p3 = (MCUR[mt].w != 0) ? __expf(st[mt][3]) : 0.f;                  \
      l_part += (p0 + p1) + (p2 + p3);                                         \
      uint32_t lo = (uint32_t)f2bf(p0) | ((uint32_t)f2bf(p1) << 16);           \
      uint32_t hi = (uint32_t)f2bf(p2) | ((uint32_t)f2bf(p3) << 16);           \
      uint2 pk; pk.x = lo; pk.y = hi;                                          \
      *(uint2*)&p_row[wave][ln15][mt * 16 + quad * 4] = pk;                    \
    }                                                                          \
    /* P^T B-fragments (wave-synchronous LDS round-trip, no barrier) */        \
    bf16x8 pf0 = *(const bf16x8*)&p_row[wave][ln15][quad * 8];                 \
    bf16x8 pf1 = *(const bf16x8*)&p_row[wave][ln15][32 + quad * 8];            \
    /* O^T += V^T x P^T on buf[CUR] */                                         \
    _Pragma("unroll") for (int dt = 0; dt < 4; ++dt) {                         \
      bf16x8 vf0 = *(const bf16x8*)&v_lds[CUR][dt * 16 + ln15][quad * 8];      \
      bf16x8 vf1 = *(const bf16x8*)&v_lds[CUR][dt * 16 + ln15][32 + quad * 8]; \
      o_acc[dt] = __builtin_amdgcn_mfma_f32_16x16x32_bf16(vf0, pf0, o_acc[dt], 0, 0, 0); \
      o_acc[dt] = __builtin_amdgcn_mfma_f32_16x16x32_bf16(vf1, pf1, o_acc[dt], 0, 0, 0); \
    }                                                                          \
    /* raw barrier: lgkmcnt-only drain; VMEM stays in flight across it */      \
    asm volatile("s_waitcnt lgkmcnt(0)\n\ts_barrier" ::: "memory");            \
  }

__global__ __launch_bounds__(256) void attn_kernel(
    const float* __restrict__ q, const int* __restrict__ mask,
    const unsigned short* __restrict__ k_bf, const unsigned short* __restrict__ v_t,
    float* __restrict__ out) {
  __shared__ __align__(16) unsigned short k_lds[2][64][72];  // [buf][key][dim]
  __shared__ __align__(16) unsigned short v_lds[2][64][72];  // [buf][dim][key]
  __shared__ __align__(16) unsigned short p_row[4][16][72];  // per-wave [qrow][key]

  // XCD-aware bijective swizzle: gridDim.x = 512 = 8 XCDs x 64 slots.
  // HW round-robins blockIdx over XCDs (xcd = n % 8); give each XCD 2
  // batches so its K/V bf16 working set (2 x 512 KiB) is L2-resident
  // instead of spilling 8.4 MB to L3 against the mask stream.
  int n = blockIdx.x;
  int xcd = n & 7;
  int slot = n >> 3;            // 0..63
  int b = (xcd << 1) | (slot >> 5);
  int o_blk = slot & 31;

  int t = threadIdx.x;
  int wave = t >> 6;
  int lane = t & 63;
  int ln15 = lane & 15;
  int quad = lane >> 4;

  int o0 = o_blk * 64 + wave * 16;
  int qrow = o0 + ln15;

  // Q B-fragments, scale 1/8 folded in
  bf16x8 qf[2];
  {
    const float* qp = q + ((size_t)b * TO + qrow) * DH;
#pragma unroll
    for (int kc = 0; kc < 2; ++kc) {
      int kk = kc * 32 + quad * 8;
      float4 f0 = *(const float4*)(qp + kk);
      float4 f1 = *(const float4*)(qp + kk + 4);
      bf16x8 a;
      a[0] = (short)f2bf(f0.x * 0.125f);
      a[1] = (short)f2bf(f0.y * 0.125f);
      a[2] = (short)f2bf(f0.z * 0.125f);
      a[3] = (short)f2bf(f0.w * 0.125f);
      a[4] = (short)f2bf(f1.x * 0.125f);
      a[5] = (short)f2bf(f1.y * 0.125f);
      a[6] = (short)f2bf(f1.z * 0.125f);
      a[7] = (short)f2bf(f1.w * 0.125f);
      qf[kc] = a;
    }
  }

  f32x4 o_acc[4];
#pragma unroll
  for (int dt = 0; dt < 4; ++dt) o_acc[dt] = (f32x4){0.f, 0.f, 0.f, 0.f};
  float l_part = 0.f;

  int row = t >> 2, part = t & 3;
  const uint4* kp = (const uint4*)(k_bf + ((size_t)b * TI + row) * DH + part * 16);
  const uint4* vp = (const uint4*)(v_t + ((size_t)b * DH + row) * TI + part * 16);
  const int* mbase = mask + ((size_t)b * TO + qrow) * TI + quad * 4;

  // ---- pipeline prologue ----
  // chunk 0 -> regs -> buf0
  uint4 ka0 = kp[0], ka1 = kp[1];
  uint4 va0 = vp[0], va1 = vp[1];
  kp = (const uint4*)((const char*)kp + 64 * DH * 2);
  vp = (const uint4*)((const char*)vp + 64 * 2);
  *(uint4*)&k_lds[0][row][part * 16] = ka0;
  *(uint4*)&k_lds[0][row][part * 16 + 8] = ka1;
  *(uint4*)&v_lds[0][row][part * 16] = va0;
  *(uint4*)&v_lds[0][row][part * 16 + 8] = va1;
  // chunk 1 -> regs (in flight across iter 0's compute)
  ka0 = kp[0]; ka1 = kp[1];
  va0 = vp[0]; va1 = vp[1];
  kp = (const uint4*)((const char*)kp + 64 * DH * 2);
  vp = (const uint4*)((const char*)vp + 64 * 2);
  // mask for iter 0 (static double-buffer mv/mw, rotated by the x2 unroll)
  int4 mv[4], mw[4];
#pragma unroll
  for (int mt = 0; mt < 4; ++mt) mv[mt] = *(const int4*)(mbase + mt * 16);
  mbase += 64;
  // buf0 visible; lgkm-only drain (VMEM above has no cross-wave consumer)
  asm volatile("s_waitcnt lgkmcnt(0)\n\ts_barrier" ::: "memory");

  for (int ic = 0; ic < NITER; ic += 2) {
    ATTN_BODY(0, ic, mv, mw)
    ATTN_BODY(1, ic + 1, mw, mv)
  }

  // epilogue
  l_part += __shfl_xor(l_part, 16);
  l_part += __shfl_xor(l_part, 32);
  float inv = 1.0f / l_part;
  float* orow = out + ((size_t)b * TO + qrow) * DH;
#pragma unroll
  for (int dt = 0; dt < 4; ++dt) {
    float4 vout;
    vout.x = o_acc[dt][0] * inv;
    vout.y = o_acc[dt][1] * inv;
    vout.z = o_acc[dt][2] * inv;
    vout.w = o_acc[dt][3] * inv;
    *(float4*)(orow + dt * 16 + quad * 4) = vout;
  }
}

extern "C" void kernel_launch(void* const* d_in, const int* in_sizes, int n_in,
                              void* d_out, int out_size, void* d_ws, size_t ws_size,
                              hipStream_t stream) {
  const float* q = (const float*)d_in[0];
  const float* k = (const float*)d_in[1];
  const float* v = (const float*)d_in[2];
  const int* mask = (const int*)d_in[3];

  unsigned short* k_bf = (unsigned short*)d_ws;             // 4 MB
  unsigned short* v_t = k_bf + (size_t)BATCH * TI * DH;     // 4 MB

  convert_kv<<<dim3(TI / 64, BATCH), 256, 0, stream>>>(k, v, k_bf, v_t);
  attn_kernel<<<dim3(TO / 64 * BATCH), 256, 0, stream>>>(q, mask, k_bf, v_t, (float*)d_out);
}